// Round 18
// baseline (557.898 us; speedup 1.0000x reference)
//
#include <hip/hip_runtime.h>

#define N_NODES 100000
#define N_EDGES 3200000
#define EPS 1e-5f
#define NODE_BLOCKS 391   // ceil(100000/256)
#define NB 782            // buckets of 128 nodes (dst >> 7)
#define BSTRIDE 4608      // fixed bucket region: mean 4096 + 8 sigma
#define NSUB 9            // chunks of 512 slots per bucket (9*512 = 4608)
#define S1_EPB 8192
#define S1_BLOCKS 391     // x 8192 edges per block

typedef float v2f __attribute__((ext_vector_type(2)));
static __device__ __forceinline__ v2f splat(float x) { v2f v; v.x = x; v.y = x; return v; }

// ---- workspace layout (bytes) ----
#define OFF_STATS  0          // 8 doubles (bn sums)          [zeroed]
#define OFF_BCNT   1024       // int[782] bucket counts       [zeroed]
#define OFF_INVCNT 5120       // float[100000]
#define OFF_AGG1   405120     // float2[100000]
#define OFF_W1T    1205120    // w1 transposed (256 floats)
#define OFF_V1T    1206144    // dw1 transposed (128 floats)
#define OFF_BUCKET 1214848    // int[782*4608] packed entries s|(dloc<<17) (14.4 MB)
#define OFF_PENC   15629696   // float2[7038*128] enc partials (7.2 MB)
#define OFF_PCNT   22836608   // int[7038*128]   count partials (3.6 MB)
#define OFF_PDEC   26440064   // float4[7038*128] dec partials (14.4 MB)
// total ≈ 40.9 MB

__global__ __launch_bounds__(256) void k_bn_stats(const float* __restrict__ x,
                                                  double* __restrict__ stats) {
    int i = blockIdx.x * 256 + threadIdx.x;
    float4 v = make_float4(0.f, 0.f, 0.f, 0.f);
    if (i < N_NODES) v = ((const float4*)x)[i];
    double a[8];
    a[0] = v.x; a[1] = v.y; a[2] = v.z; a[3] = v.w;
    a[4] = (double)v.x * v.x; a[5] = (double)v.y * v.y;
    a[6] = (double)v.z * v.z; a[7] = (double)v.w * v.w;
    #pragma unroll
    for (int off = 32; off > 0; off >>= 1) {
        #pragma unroll
        for (int j = 0; j < 8; j++) a[j] += __shfl_down(a[j], off);
    }
    __shared__ double smem[4][8];
    int wave = threadIdx.x >> 6;
    int lane = threadIdx.x & 63;
    if (lane == 0) {
        #pragma unroll
        for (int j = 0; j < 8; j++) smem[wave][j] = a[j];
    }
    __syncthreads();
    if (threadIdx.x == 0) {
        #pragma unroll
        for (int j = 0; j < 8; j++) {
            double t = smem[0][j] + smem[1][j] + smem[2][j] + smem[3][j];
            atomicAdd(&stats[j], t);
        }
    }
}

// transpose layer-1 weights only (layer-2 k-outer uses the ORIGINAL w2 layout)
__global__ __launch_bounds__(256) void k_prep(const float* __restrict__ ew1,
                                              const float* __restrict__ dw1,
                                              float* __restrict__ w1t,
                                              float* __restrict__ v1t) {
    int t = threadIdx.x;
    { int j = t >> 3, k = t & 7; w1t[j * 8 + k] = ew1[k * 32 + j]; }
    if (t < 128) { int j = t >> 2, k = t & 3; v1t[j * 4 + k] = dw1[k * 32 + j]; }
}

// S1: bin edges by bucket = dst>>7 into fixed-stride regions, 4B packed
// entries s|(dloc<<17). histogram -> in-block scan -> one global fetch_add per
// (block,bucket) -> LDS-sorted placement -> coalesced write-out.
__global__ __launch_bounds__(256) void k_s1(const int* __restrict__ ei,
                                            int* __restrict__ bcnt,
                                            int* __restrict__ bucket_buf) {
    __shared__ int hist[NB];
    __shared__ int base[NB];
    __shared__ int run[NB];
    __shared__ int gbase[NB];
    __shared__ int entries[S1_EPB];
    __shared__ unsigned short bk16[S1_EPB];
    __shared__ int wsum[4];
    int tid = threadIdx.x;
    int e0 = blockIdx.x * S1_EPB;
    for (int i = tid; i < NB; i += 256) hist[i] = 0;
    __syncthreads();
    #pragma unroll
    for (int k = 0; k < 32; k++) {
        int e = e0 + k * 256 + tid;
        if (e < N_EDGES) atomicAdd(&hist[ei[N_EDGES + e] >> 7], 1);
    }
    __syncthreads();
    int t4 = tid * 4;
    int h0 = (t4 + 0 < NB) ? hist[t4 + 0] : 0;
    int h1 = (t4 + 1 < NB) ? hist[t4 + 1] : 0;
    int h2 = (t4 + 2 < NB) ? hist[t4 + 2] : 0;
    int h3 = (t4 + 3 < NB) ? hist[t4 + 3] : 0;
    int tsum = h0 + h1 + h2 + h3;
    int lane = tid & 63, wv = tid >> 6;
    int xs = tsum;
    #pragma unroll
    for (int off = 1; off < 64; off <<= 1) {
        int u = __shfl_up(xs, off);
        if (lane >= off) xs += u;
    }
    if (lane == 63) wsum[wv] = xs;
    __syncthreads();
    int wo = 0;
    #pragma unroll
    for (int w = 0; w < 4; w++) if (w < wv) wo += wsum[w];
    int texcl = wo + xs - tsum;
    if (t4 + 0 < NB) base[t4 + 0] = texcl;
    if (t4 + 1 < NB) base[t4 + 1] = texcl + h0;
    if (t4 + 2 < NB) base[t4 + 2] = texcl + h0 + h1;
    if (t4 + 3 < NB) base[t4 + 3] = texcl + h0 + h1 + h2;
    __syncthreads();
    for (int i = tid; i < NB; i += 256) {
        int h = hist[i];
        gbase[i] = i * BSTRIDE + (h ? atomicAdd(&bcnt[i], h) : 0);
        run[i] = base[i];
    }
    __syncthreads();
    #pragma unroll
    for (int k = 0; k < 32; k++) {
        int e = e0 + k * 256 + tid;
        if (e < N_EDGES) {
            int s = ei[e];
            int d = ei[N_EDGES + e];
            int b = d >> 7;
            int r = atomicAdd(&run[b], 1);   // LDS
            entries[r] = s | ((d & 127) << 17);
            bk16[r] = (unsigned short)b;
        }
    }
    __syncthreads();
    int nloc = min(S1_EPB, N_EDGES - e0);
    for (int idx = tid; idx < nloc; idx += 256) {
        int b = bk16[idx];
        bucket_buf[gbase[b] + (idx - base[b])] = entries[idx];
    }
}

// Fused BN + encoder (8->32->32->2, relu x3) + per-chunk partial aggregation.
// Permuted slot assignment (tid*85 mod 256) de-correlates the dst-sorted
// layout so a wave's LDS atomics hit ~64 distinct addresses (R17: 137->115us).
// Layer-2 is K-OUTER with the j-dimension SPLIT IN HALF: only acc[16] v2f
// (32 regs) of intermediate state is live, halving the unified VGPR+AGPR
// footprint (~108 -> ~80) to lift occupancy from 4 to ~6 waves/SIMD.
// Layer-1 is recomputed per half (+~20% inst) - trading issue for latency hiding.
// (256,5): cap 102 unified regs; NEVER cap below the live set (R13: spill 15x).
__global__ __launch_bounds__(256, 5) void k_enc_partial(const float* __restrict__ x,
                                                        const double* __restrict__ stats,
                                                        const float* __restrict__ bn_w,
                                                        const float* __restrict__ bn_b,
                                                        const int* __restrict__ bucket_buf,
                                                        const int* __restrict__ bcnt,
                                                        float2* __restrict__ penc,
                                                        int* __restrict__ pcnt,
                                                        const float* __restrict__ w1t,
                                                        const float* __restrict__ b1,
                                                        const float* __restrict__ w2,
                                                        const float* __restrict__ b2,
                                                        const float* __restrict__ w3,
                                                        const float* __restrict__ b3) {
    __shared__ float acc0[128], acc1[128];
    __shared__ int lc[128];
    int b = blockIdx.x;
    int sub = blockIdx.y;
    int tid = threadIdx.x;
    int cb = bcnt[b];
    int p = (tid * 85) & 255;            // bijection on 0..255
    int gbase = sub * 512 + 2 * p;
    if (tid < 128) { acc0[tid] = 0.f; acc1[tid] = 0.f; lc[tid] = 0; }
    __syncthreads();

    const double inv_n = 1.0 / (double)N_NODES;
    float sc[4], sh2[4];
    #pragma unroll
    for (int d = 0; d < 4; d++) {
        double m  = stats[d] * inv_n;
        double vr = stats[4 + d] * inv_n - m * m;
        float rs  = (float)(1.0 / sqrt(vr + (double)EPS));
        sc[d]  = rs * bn_w[d];
        sh2[d] = bn_b[d] - (float)m * sc[d];
    }

    bool vA = (gbase < cb);
    bool vB = (gbase + 1 < cb);
    if (vA) {
        int node0 = b << 7;
        int2 q = *(const int2*)&bucket_buf[b * BSTRIDE + gbase];  // 8B aligned
        int eA = q.x;
        int eB = vB ? q.y : q.x;
        int sA = eA & 0x1FFFF, iA = (eA >> 17) & 127;
        int sB = eB & 0x1FFFF, iB = (eB >> 17) & 127;
        float4 xiA = ((const float4*)x)[node0 + iA];
        float4 xjA = ((const float4*)x)[sA];
        float4 xiB = ((const float4*)x)[node0 + iB];
        float4 xjB = ((const float4*)x)[sB];
        v2f in[8];
        in[0].x = xiA.x; in[0].y = xiB.x;
        in[1].x = xiA.y; in[1].y = xiB.y;
        in[2].x = xiA.z; in[2].y = xiB.z;
        in[3].x = xiA.w; in[3].y = xiB.w;
        #pragma unroll
        for (int d = 0; d < 4; d++)
            in[d] = __builtin_elementwise_fma(in[d], splat(sc[d]), splat(sh2[d]));
        in[4].x = xjA.x - xiA.x; in[4].y = xjB.x - xiB.x;
        in[5].x = xjA.y - xiA.y; in[5].y = xjB.y - xiB.y;
        in[6].x = xjA.z - xiA.z; in[6].y = xjB.z - xiB.z;
        in[7].x = xjA.w - xiA.w; in[7].y = xjB.w - xiB.w;
        #pragma unroll
        for (int d = 0; d < 4; d++)
            in[4 + d] = in[4 + d] * splat(sc[d]);

        v2f o0 = splat(b3[0]), o1 = splat(b3[1]);
        #pragma unroll
        for (int jh = 0; jh < 2; jh++) {
            v2f acc[16];
            #pragma unroll
            for (int j = 0; j < 16; j++) acc[j] = splat(0.f);
            #pragma unroll
            for (int k = 0; k < 32; k++) {
                v2f h = splat(b1[k]);
                v2f g = splat(0.f);
                #pragma unroll
                for (int m = 0; m < 4; m++) {
                    h = __builtin_elementwise_fma(in[m],     splat(w1t[k * 8 + m]),     h);
                    g = __builtin_elementwise_fma(in[m + 4], splat(w1t[k * 8 + m + 4]), g);
                }
                h = __builtin_elementwise_max(h + g, splat(0.f));
                #pragma unroll
                for (int j = 0; j < 16; j++)
                    acc[j] = __builtin_elementwise_fma(h, splat(w2[k * 32 + jh * 16 + j]), acc[j]);
            }
            #pragma unroll
            for (int j = 0; j < 16; j++) {
                int jj = jh * 16 + j;
                v2f a = __builtin_elementwise_max(acc[j] + splat(b2[jj]), splat(0.f));
                o0 = __builtin_elementwise_fma(a, splat(w3[2 * jj + 0]), o0);
                o1 = __builtin_elementwise_fma(a, splat(w3[2 * jj + 1]), o1);
            }
        }
        o0 = __builtin_elementwise_max(o0, splat(0.f));
        o1 = __builtin_elementwise_max(o1, splat(0.f));

        atomicAdd(&acc0[iA], o0.x);
        atomicAdd(&acc1[iA], o1.x);
        atomicAdd(&lc[iA], 1);
        if (vB) {
            atomicAdd(&acc0[iB], o0.y);
            atomicAdd(&acc1[iB], o1.y);
            atomicAdd(&lc[iB], 1);
        }
    }
    __syncthreads();
    if (tid < 128) {
        int pb = b * NSUB + sub;
        penc[pb * 128 + tid] = make_float2(acc0[tid], acc1[tid]);
        pcnt[pb * 128 + tid] = lc[tid];
    }
}

// sum 9 chunk-partials per node -> agg1 (mean) + invcnt
__global__ __launch_bounds__(256) void k_reduce_enc_p(const float2* __restrict__ penc,
                                                      const int* __restrict__ pcnt,
                                                      float2* __restrict__ agg1,
                                                      float* __restrict__ invcnt) {
    int i = blockIdx.x * 256 + threadIdx.x;
    if (i >= N_NODES) return;
    int b = i >> 7, l = i & 127;
    float a0 = 0.f, a1 = 0.f;
    int c = 0;
    #pragma unroll
    for (int sub = 0; sub < NSUB; sub++) {
        int idx = (b * NSUB + sub) * 128 + l;
        float2 p = penc[idx];
        a0 += p.x; a1 += p.y;
        c += pcnt[idx];
    }
    float ic = 1.0f / (float)(c > 1 ? c : 1);
    invcnt[i] = ic;
    agg1[i] = make_float2(a0 * ic, a1 * ic);
}

// Fused decoder (4->32->32->4, relu first two) + per-chunk partials.
// Same permuted slots + j-half-split k-outer structure as the encoder.
__global__ __launch_bounds__(256, 5) void k_dec_partial(const float2* __restrict__ henc,
                                                        const int* __restrict__ bucket_buf,
                                                        const int* __restrict__ bcnt,
                                                        float4* __restrict__ pdec,
                                                        const float* __restrict__ v1t,
                                                        const float* __restrict__ b1,
                                                        const float* __restrict__ w2,
                                                        const float* __restrict__ b2,
                                                        const float* __restrict__ w3,
                                                        const float* __restrict__ b3) {
    __shared__ float a0s[128], a1s[128], a2s[128], a3s[128];
    int b = blockIdx.x;
    int sub = blockIdx.y;
    int tid = threadIdx.x;
    int cb = bcnt[b];
    int p = (tid * 85) & 255;            // bijection on 0..255
    int gbase = sub * 512 + 2 * p;
    if (tid < 128) { a0s[tid] = 0.f; a1s[tid] = 0.f; a2s[tid] = 0.f; a3s[tid] = 0.f; }
    __syncthreads();

    bool vA = (gbase < cb);
    bool vB = (gbase + 1 < cb);
    if (vA) {
        int node0 = b << 7;
        int2 q = *(const int2*)&bucket_buf[b * BSTRIDE + gbase];
        int eA = q.x;
        int eB = vB ? q.y : q.x;
        int sA = eA & 0x1FFFF, iA = (eA >> 17) & 127;
        int sB = eB & 0x1FFFF, iB = (eB >> 17) & 127;
        float2 hiA = henc[node0 + iA];
        float2 hjA = henc[sA];
        float2 hiB = henc[node0 + iB];
        float2 hjB = henc[sB];
        v2f in[4];
        in[0].x = hiA.x;         in[0].y = hiB.x;
        in[1].x = hiA.y;         in[1].y = hiB.y;
        in[2].x = hjA.x - hiA.x; in[2].y = hjB.x - hiB.x;
        in[3].x = hjA.y - hiA.y; in[3].y = hjB.y - hiB.y;

        v2f o0 = splat(b3[0]), o1 = splat(b3[1]), o2 = splat(b3[2]), o3 = splat(b3[3]);
        #pragma unroll
        for (int jh = 0; jh < 2; jh++) {
            v2f acc[16];
            #pragma unroll
            for (int j = 0; j < 16; j++) acc[j] = splat(0.f);
            #pragma unroll
            for (int k = 0; k < 32; k++) {
                v2f h = splat(b1[k]);
                v2f g = splat(0.f);
                h = __builtin_elementwise_fma(in[0], splat(v1t[k * 4 + 0]), h);
                g = __builtin_elementwise_fma(in[1], splat(v1t[k * 4 + 1]), g);
                h = __builtin_elementwise_fma(in[2], splat(v1t[k * 4 + 2]), h);
                g = __builtin_elementwise_fma(in[3], splat(v1t[k * 4 + 3]), g);
                h = __builtin_elementwise_max(h + g, splat(0.f));
                #pragma unroll
                for (int j = 0; j < 16; j++)
                    acc[j] = __builtin_elementwise_fma(h, splat(w2[k * 32 + jh * 16 + j]), acc[j]);
            }
            #pragma unroll
            for (int j = 0; j < 16; j++) {
                int jj = jh * 16 + j;
                v2f a = __builtin_elementwise_max(acc[j] + splat(b2[jj]), splat(0.f));
                o0 = __builtin_elementwise_fma(a, splat(w3[4 * jj + 0]), o0);
                o1 = __builtin_elementwise_fma(a, splat(w3[4 * jj + 1]), o1);
                o2 = __builtin_elementwise_fma(a, splat(w3[4 * jj + 2]), o2);
                o3 = __builtin_elementwise_fma(a, splat(w3[4 * jj + 3]), o3);
            }
        }
        atomicAdd(&a0s[iA], o0.x);
        atomicAdd(&a1s[iA], o1.x);
        atomicAdd(&a2s[iA], o2.x);
        atomicAdd(&a3s[iA], o3.x);
        if (vB) {
            atomicAdd(&a0s[iB], o0.y);
            atomicAdd(&a1s[iB], o1.y);
            atomicAdd(&a2s[iB], o2.y);
            atomicAdd(&a3s[iB], o3.y);
        }
    }
    __syncthreads();
    if (tid < 128) {
        int pb = b * NSUB + sub;
        pdec[pb * 128 + tid] = make_float4(a0s[tid], a1s[tid], a2s[tid], a3s[tid]);
    }
}

// sum 9 chunk-partials per node -> final output (mean)
__global__ __launch_bounds__(256) void k_reduce_dec_p(const float4* __restrict__ pdec,
                                                      const float* __restrict__ invcnt,
                                                      float4* __restrict__ out) {
    int i = blockIdx.x * 256 + threadIdx.x;
    if (i >= N_NODES) return;
    int b = i >> 7, l = i & 127;
    float a0 = 0.f, a1 = 0.f, a2 = 0.f, a3 = 0.f;
    #pragma unroll
    for (int sub = 0; sub < NSUB; sub++) {
        float4 p = pdec[(b * NSUB + sub) * 128 + l];
        a0 += p.x; a1 += p.y; a2 += p.z; a3 += p.w;
    }
    float ic = invcnt[i];
    out[i] = make_float4(a0 * ic, a1 * ic, a2 * ic, a3 * ic);
}

extern "C" void kernel_launch(void* const* d_in, const int* in_sizes, int n_in,
                              void* d_out, int out_size, void* d_ws, size_t ws_size,
                              hipStream_t stream) {
    const float* x    = (const float*)d_in[0];
    const int*   ei   = (const int*)d_in[1];
    const float* bn_w = (const float*)d_in[2];
    const float* bn_b = (const float*)d_in[3];
    const float* ew1  = (const float*)d_in[4];
    const float* eb1  = (const float*)d_in[5];
    const float* ew2  = (const float*)d_in[6];
    const float* eb2  = (const float*)d_in[7];
    const float* ew3  = (const float*)d_in[8];
    const float* eb3  = (const float*)d_in[9];
    const float* dw1  = (const float*)d_in[10];
    const float* db1  = (const float*)d_in[11];
    const float* dw2  = (const float*)d_in[12];
    const float* db2  = (const float*)d_in[13];
    const float* dw3  = (const float*)d_in[14];
    const float* db3  = (const float*)d_in[15];

    char* ws = (char*)d_ws;
    double* stats      = (double*)(ws + OFF_STATS);
    int*    bcnt       = (int*)(ws + OFF_BCNT);
    float*  invcnt     = (float*)(ws + OFF_INVCNT);
    float2* agg1       = (float2*)(ws + OFF_AGG1);
    float*  w1t        = (float*)(ws + OFF_W1T);
    float*  v1t        = (float*)(ws + OFF_V1T);
    int*    bucket_buf = (int*)(ws + OFF_BUCKET);
    float2* penc       = (float2*)(ws + OFF_PENC);
    int*    pcnt       = (int*)(ws + OFF_PCNT);
    float4* pdec       = (float4*)(ws + OFF_PDEC);
    float4* out        = (float4*)d_out;

    // zero: stats + bucket counts, contiguous [0, 5120)
    hipMemsetAsync(ws, 0, 5120, stream);

    k_prep<<<1, 256, 0, stream>>>(ew1, dw1, w1t, v1t);
    k_bn_stats<<<NODE_BLOCKS, 256, 0, stream>>>(x, stats);
    k_s1<<<S1_BLOCKS, 256, 0, stream>>>(ei, bcnt, bucket_buf);
    k_enc_partial<<<dim3(NB, NSUB), 256, 0, stream>>>(x, stats, bn_w, bn_b,
                                                      bucket_buf, bcnt, penc, pcnt,
                                                      w1t, eb1, ew2, eb2, ew3, eb3);
    k_reduce_enc_p<<<NODE_BLOCKS, 256, 0, stream>>>(penc, pcnt, agg1, invcnt);
    k_dec_partial<<<dim3(NB, NSUB), 256, 0, stream>>>(agg1, bucket_buf, bcnt, pdec,
                                                      v1t, db1, dw2, db2, dw3, db3);
    k_reduce_dec_p<<<NODE_BLOCKS, 256, 0, stream>>>(pdec, invcnt, out);
}

// Round 19
// 367.732 us; speedup vs baseline: 1.5171x; 1.5171x over previous
//
#include <hip/hip_runtime.h>

#define N_NODES 100000
#define N_EDGES 3200000
#define EPS 1e-5f
#define NODE_BLOCKS 391   // ceil(100000/256)
#define NB 782            // buckets of 128 nodes (dst >> 7)
#define BSTRIDE 4608      // fixed bucket region: mean 4096 + 8 sigma
#define NSUB 9            // chunks of 512 slots per bucket (9*512 = 4608)
#define S1_EPB 8192
#define S1_BLOCKS 391     // x 8192 edges per block

typedef float v2f __attribute__((ext_vector_type(2)));
static __device__ __forceinline__ v2f splat(float x) { v2f v; v.x = x; v.y = x; return v; }

// ---- workspace layout (bytes) ----
#define OFF_STATS  0          // 8 doubles (bn sums)          [zeroed]
#define OFF_BCNT   1024       // int[782] bucket counts       [zeroed]
#define OFF_INVCNT 5120       // float[100000]
#define OFF_AGG1   405120     // float2[100000]
#define OFF_W1T    1205120    // transposed weights
#define OFF_W2T    1206144
#define OFF_V1T    1210240
#define OFF_V2T    1210752
#define OFF_BUCKET 1214848    // int[782*4608] packed entries s|(dloc<<17) (14.4 MB)
#define OFF_PENC   15629696   // float2[7038*128] enc partials (7.2 MB)
#define OFF_PCNT   22836608   // int[7038*128]   count partials (3.6 MB)
#define OFF_PDEC   26440064   // float4[7038*128] dec partials (14.4 MB)
// total ≈ 40.9 MB

__global__ __launch_bounds__(256) void k_bn_stats(const float* __restrict__ x,
                                                  double* __restrict__ stats) {
    int i = blockIdx.x * 256 + threadIdx.x;
    float4 v = make_float4(0.f, 0.f, 0.f, 0.f);
    if (i < N_NODES) v = ((const float4*)x)[i];
    double a[8];
    a[0] = v.x; a[1] = v.y; a[2] = v.z; a[3] = v.w;
    a[4] = (double)v.x * v.x; a[5] = (double)v.y * v.y;
    a[6] = (double)v.z * v.z; a[7] = (double)v.w * v.w;
    #pragma unroll
    for (int off = 32; off > 0; off >>= 1) {
        #pragma unroll
        for (int j = 0; j < 8; j++) a[j] += __shfl_down(a[j], off);
    }
    __shared__ double smem[4][8];
    int wave = threadIdx.x >> 6;
    int lane = threadIdx.x & 63;
    if (lane == 0) {
        #pragma unroll
        for (int j = 0; j < 8; j++) smem[wave][j] = a[j];
    }
    __syncthreads();
    if (threadIdx.x == 0) {
        #pragma unroll
        for (int j = 0; j < 8; j++) {
            double t = smem[0][j] + smem[1][j] + smem[2][j] + smem[3][j];
            atomicAdd(&stats[j], t);
        }
    }
}

// transpose weights so the streaming-j MLP form reads contiguous scalar rows
__global__ __launch_bounds__(1024) void k_prep(const float* __restrict__ ew1,
                                               const float* __restrict__ ew2,
                                               const float* __restrict__ dw1,
                                               const float* __restrict__ dw2,
                                               float* __restrict__ w1t,
                                               float* __restrict__ w2t,
                                               float* __restrict__ v1t,
                                               float* __restrict__ v2t) {
    int t = threadIdx.x;
    { int j = t >> 5, k = t & 31; w2t[j * 32 + k] = ew2[k * 32 + j]; }
    { int j = t >> 5, k = t & 31; v2t[j * 32 + k] = dw2[k * 32 + j]; }
    if (t < 256) { int j = t >> 3, k = t & 7; w1t[j * 8 + k] = ew1[k * 32 + j]; }
    if (t < 128) { int j = t >> 2, k = t & 3; v1t[j * 4 + k] = dw1[k * 32 + j]; }
}

// S1: bin edges by bucket = dst>>7 into fixed-stride regions, 4B packed
// entries s|(dloc<<17). histogram -> in-block scan -> one global fetch_add per
// (block,bucket) -> LDS-sorted placement -> coalesced write-out.
__global__ __launch_bounds__(256) void k_s1(const int* __restrict__ ei,
                                            int* __restrict__ bcnt,
                                            int* __restrict__ bucket_buf) {
    __shared__ int hist[NB];
    __shared__ int base[NB];
    __shared__ int run[NB];
    __shared__ int gbase[NB];
    __shared__ int entries[S1_EPB];
    __shared__ unsigned short bk16[S1_EPB];
    __shared__ int wsum[4];
    int tid = threadIdx.x;
    int e0 = blockIdx.x * S1_EPB;
    for (int i = tid; i < NB; i += 256) hist[i] = 0;
    __syncthreads();
    #pragma unroll
    for (int k = 0; k < 32; k++) {
        int e = e0 + k * 256 + tid;
        if (e < N_EDGES) atomicAdd(&hist[ei[N_EDGES + e] >> 7], 1);
    }
    __syncthreads();
    int t4 = tid * 4;
    int h0 = (t4 + 0 < NB) ? hist[t4 + 0] : 0;
    int h1 = (t4 + 1 < NB) ? hist[t4 + 1] : 0;
    int h2 = (t4 + 2 < NB) ? hist[t4 + 2] : 0;
    int h3 = (t4 + 3 < NB) ? hist[t4 + 3] : 0;
    int tsum = h0 + h1 + h2 + h3;
    int lane = tid & 63, wv = tid >> 6;
    int xs = tsum;
    #pragma unroll
    for (int off = 1; off < 64; off <<= 1) {
        int u = __shfl_up(xs, off);
        if (lane >= off) xs += u;
    }
    if (lane == 63) wsum[wv] = xs;
    __syncthreads();
    int wo = 0;
    #pragma unroll
    for (int w = 0; w < 4; w++) if (w < wv) wo += wsum[w];
    int texcl = wo + xs - tsum;
    if (t4 + 0 < NB) base[t4 + 0] = texcl;
    if (t4 + 1 < NB) base[t4 + 1] = texcl + h0;
    if (t4 + 2 < NB) base[t4 + 2] = texcl + h0 + h1;
    if (t4 + 3 < NB) base[t4 + 3] = texcl + h0 + h1 + h2;
    __syncthreads();
    for (int i = tid; i < NB; i += 256) {
        int h = hist[i];
        gbase[i] = i * BSTRIDE + (h ? atomicAdd(&bcnt[i], h) : 0);
        run[i] = base[i];
    }
    __syncthreads();
    #pragma unroll
    for (int k = 0; k < 32; k++) {
        int e = e0 + k * 256 + tid;
        if (e < N_EDGES) {
            int s = ei[e];
            int d = ei[N_EDGES + e];
            int b = d >> 7;
            int r = atomicAdd(&run[b], 1);   // LDS
            entries[r] = s | ((d & 127) << 17);
            bk16[r] = (unsigned short)b;
        }
    }
    __syncthreads();
    int nloc = min(S1_EPB, N_EDGES - e0);
    for (int idx = tid; idx < nloc; idx += 256) {
        int b = bk16[idx];
        bucket_buf[gbase[b] + (idx - base[b])] = entries[idx];
    }
}

// Fused BN + encoder (8->32->32->2, relu x3) + per-chunk partial aggregation.
// Permuted slot assignment (tid*85 mod 256) de-correlates the dst-sorted
// layout so a wave's LDS atomics hit ~64 distinct addresses (R17: 137->115us;
// same-address LDS atomic RMWs serialize across lanes).
// (256,4): MLP live set ~70-110 unified (VGPR+AGPR) regs; NEVER cap below it
// (R13: cap 64 => full spill, 15x; R18: cap 102 => spill, 2x).
__global__ __launch_bounds__(256, 4) void k_enc_partial(const float* __restrict__ x,
                                                        const double* __restrict__ stats,
                                                        const float* __restrict__ bn_w,
                                                        const float* __restrict__ bn_b,
                                                        const int* __restrict__ bucket_buf,
                                                        const int* __restrict__ bcnt,
                                                        float2* __restrict__ penc,
                                                        int* __restrict__ pcnt,
                                                        const float* __restrict__ w1t,
                                                        const float* __restrict__ b1,
                                                        const float* __restrict__ w2t,
                                                        const float* __restrict__ b2,
                                                        const float* __restrict__ w3,
                                                        const float* __restrict__ b3) {
    __shared__ float acc0[128], acc1[128];
    __shared__ int lc[128];
    int b = blockIdx.x;
    int sub = blockIdx.y;
    int tid = threadIdx.x;
    int cb = bcnt[b];
    int p = (tid * 85) & 255;            // bijection on 0..255
    int gbase = sub * 512 + 2 * p;
    if (tid < 128) { acc0[tid] = 0.f; acc1[tid] = 0.f; lc[tid] = 0; }
    __syncthreads();

    const double inv_n = 1.0 / (double)N_NODES;
    float sc[4], sh2[4];
    #pragma unroll
    for (int d = 0; d < 4; d++) {
        double m  = stats[d] * inv_n;
        double vr = stats[4 + d] * inv_n - m * m;
        float rs  = (float)(1.0 / sqrt(vr + (double)EPS));
        sc[d]  = rs * bn_w[d];
        sh2[d] = bn_b[d] - (float)m * sc[d];
    }

    bool vA = (gbase < cb);
    bool vB = (gbase + 1 < cb);
    if (vA) {
        int node0 = b << 7;
        int2 q = *(const int2*)&bucket_buf[b * BSTRIDE + gbase];  // 8B aligned
        int eA = q.x;
        int eB = vB ? q.y : q.x;
        int sA = eA & 0x1FFFF, iA = (eA >> 17) & 127;
        int sB = eB & 0x1FFFF, iB = (eB >> 17) & 127;
        float4 xiA = ((const float4*)x)[node0 + iA];
        float4 xjA = ((const float4*)x)[sA];
        float4 xiB = ((const float4*)x)[node0 + iB];
        float4 xjB = ((const float4*)x)[sB];
        v2f in[8];
        in[0].x = xiA.x; in[0].y = xiB.x;
        in[1].x = xiA.y; in[1].y = xiB.y;
        in[2].x = xiA.z; in[2].y = xiB.z;
        in[3].x = xiA.w; in[3].y = xiB.w;
        #pragma unroll
        for (int d = 0; d < 4; d++)
            in[d] = __builtin_elementwise_fma(in[d], splat(sc[d]), splat(sh2[d]));
        in[4].x = xjA.x - xiA.x; in[4].y = xjB.x - xiB.x;
        in[5].x = xjA.y - xiA.y; in[5].y = xjB.y - xiB.y;
        in[6].x = xjA.z - xiA.z; in[6].y = xjB.z - xiB.z;
        in[7].x = xjA.w - xiA.w; in[7].y = xjB.w - xiB.w;
        #pragma unroll
        for (int d = 0; d < 4; d++)
            in[4 + d] = in[4 + d] * splat(sc[d]);

        v2f h1[32];
        #pragma unroll
        for (int j = 0; j < 32; j++) {
            v2f a = splat(b1[j]);
            v2f a2 = splat(0.f);
            #pragma unroll
            for (int k = 0; k < 4; k++) {
                a  = __builtin_elementwise_fma(in[k],     splat(w1t[j * 8 + k]),     a);
                a2 = __builtin_elementwise_fma(in[k + 4], splat(w1t[j * 8 + k + 4]), a2);
            }
            h1[j] = __builtin_elementwise_max(a + a2, splat(0.f));
        }
        v2f o0 = splat(b3[0]), o1 = splat(b3[1]);
        #pragma unroll
        for (int j = 0; j < 32; j++) {
            v2f a = splat(b2[j]);
            v2f a2 = splat(0.f);
            #pragma unroll
            for (int k = 0; k < 16; k++) {
                a  = __builtin_elementwise_fma(h1[k],      splat(w2t[j * 32 + k]),      a);
                a2 = __builtin_elementwise_fma(h1[k + 16], splat(w2t[j * 32 + k + 16]), a2);
            }
            a = __builtin_elementwise_max(a + a2, splat(0.f));
            o0 = __builtin_elementwise_fma(a, splat(w3[2 * j + 0]), o0);
            o1 = __builtin_elementwise_fma(a, splat(w3[2 * j + 1]), o1);
        }
        o0 = __builtin_elementwise_max(o0, splat(0.f));
        o1 = __builtin_elementwise_max(o1, splat(0.f));

        atomicAdd(&acc0[iA], o0.x);
        atomicAdd(&acc1[iA], o1.x);
        atomicAdd(&lc[iA], 1);
        if (vB) {
            atomicAdd(&acc0[iB], o0.y);
            atomicAdd(&acc1[iB], o1.y);
            atomicAdd(&lc[iB], 1);
        }
    }
    __syncthreads();
    if (tid < 128) {
        int pb = b * NSUB + sub;
        penc[pb * 128 + tid] = make_float2(acc0[tid], acc1[tid]);
        pcnt[pb * 128 + tid] = lc[tid];
    }
}

// sum 9 chunk-partials per node -> agg1 (mean) + invcnt
__global__ __launch_bounds__(256) void k_reduce_enc_p(const float2* __restrict__ penc,
                                                      const int* __restrict__ pcnt,
                                                      float2* __restrict__ agg1,
                                                      float* __restrict__ invcnt) {
    int i = blockIdx.x * 256 + threadIdx.x;
    if (i >= N_NODES) return;
    int b = i >> 7, l = i & 127;
    float a0 = 0.f, a1 = 0.f;
    int c = 0;
    #pragma unroll
    for (int sub = 0; sub < NSUB; sub++) {
        int idx = (b * NSUB + sub) * 128 + l;
        float2 p = penc[idx];
        a0 += p.x; a1 += p.y;
        c += pcnt[idx];
    }
    float ic = 1.0f / (float)(c > 1 ? c : 1);
    invcnt[i] = ic;
    agg1[i] = make_float2(a0 * ic, a1 * ic);
}

// Fused decoder (4->32->32->4, relu first two) + per-chunk partials.
// Same permuted slot assignment as the encoder.
__global__ __launch_bounds__(256, 4) void k_dec_partial(const float2* __restrict__ henc,
                                                        const int* __restrict__ bucket_buf,
                                                        const int* __restrict__ bcnt,
                                                        float4* __restrict__ pdec,
                                                        const float* __restrict__ v1t,
                                                        const float* __restrict__ b1,
                                                        const float* __restrict__ v2t,
                                                        const float* __restrict__ b2,
                                                        const float* __restrict__ w3,
                                                        const float* __restrict__ b3) {
    __shared__ float a0s[128], a1s[128], a2s[128], a3s[128];
    int b = blockIdx.x;
    int sub = blockIdx.y;
    int tid = threadIdx.x;
    int cb = bcnt[b];
    int p = (tid * 85) & 255;            // bijection on 0..255
    int gbase = sub * 512 + 2 * p;
    if (tid < 128) { a0s[tid] = 0.f; a1s[tid] = 0.f; a2s[tid] = 0.f; a3s[tid] = 0.f; }
    __syncthreads();

    bool vA = (gbase < cb);
    bool vB = (gbase + 1 < cb);
    if (vA) {
        int node0 = b << 7;
        int2 q = *(const int2*)&bucket_buf[b * BSTRIDE + gbase];
        int eA = q.x;
        int eB = vB ? q.y : q.x;
        int sA = eA & 0x1FFFF, iA = (eA >> 17) & 127;
        int sB = eB & 0x1FFFF, iB = (eB >> 17) & 127;
        float2 hiA = henc[node0 + iA];
        float2 hjA = henc[sA];
        float2 hiB = henc[node0 + iB];
        float2 hjB = henc[sB];
        v2f in[4];
        in[0].x = hiA.x;         in[0].y = hiB.x;
        in[1].x = hiA.y;         in[1].y = hiB.y;
        in[2].x = hjA.x - hiA.x; in[2].y = hjB.x - hiB.x;
        in[3].x = hjA.y - hiA.y; in[3].y = hjB.y - hiB.y;

        v2f h1[32];
        #pragma unroll
        for (int j = 0; j < 32; j++) {
            v2f a = splat(b1[j]);
            v2f a2 = splat(0.f);
            a  = __builtin_elementwise_fma(in[0], splat(v1t[j * 4 + 0]), a);
            a2 = __builtin_elementwise_fma(in[1], splat(v1t[j * 4 + 1]), a2);
            a  = __builtin_elementwise_fma(in[2], splat(v1t[j * 4 + 2]), a);
            a2 = __builtin_elementwise_fma(in[3], splat(v1t[j * 4 + 3]), a2);
            h1[j] = __builtin_elementwise_max(a + a2, splat(0.f));
        }
        v2f o0 = splat(b3[0]), o1 = splat(b3[1]), o2 = splat(b3[2]), o3 = splat(b3[3]);
        #pragma unroll
        for (int j = 0; j < 32; j++) {
            v2f a = splat(b2[j]);
            v2f a2 = splat(0.f);
            #pragma unroll
            for (int k = 0; k < 16; k++) {
                a  = __builtin_elementwise_fma(h1[k],      splat(v2t[j * 32 + k]),      a);
                a2 = __builtin_elementwise_fma(h1[k + 16], splat(v2t[j * 32 + k + 16]), a2);
            }
            a = __builtin_elementwise_max(a + a2, splat(0.f));
            o0 = __builtin_elementwise_fma(a, splat(w3[4 * j + 0]), o0);
            o1 = __builtin_elementwise_fma(a, splat(w3[4 * j + 1]), o1);
            o2 = __builtin_elementwise_fma(a, splat(w3[4 * j + 2]), o2);
            o3 = __builtin_elementwise_fma(a, splat(w3[4 * j + 3]), o3);
        }
        atomicAdd(&a0s[iA], o0.x);
        atomicAdd(&a1s[iA], o1.x);
        atomicAdd(&a2s[iA], o2.x);
        atomicAdd(&a3s[iA], o3.x);
        if (vB) {
            atomicAdd(&a0s[iB], o0.y);
            atomicAdd(&a1s[iB], o1.y);
            atomicAdd(&a2s[iB], o2.y);
            atomicAdd(&a3s[iB], o3.y);
        }
    }
    __syncthreads();
    if (tid < 128) {
        int pb = b * NSUB + sub;
        pdec[pb * 128 + tid] = make_float4(a0s[tid], a1s[tid], a2s[tid], a3s[tid]);
    }
}

// sum 9 chunk-partials per node -> final output (mean)
__global__ __launch_bounds__(256) void k_reduce_dec_p(const float4* __restrict__ pdec,
                                                      const float* __restrict__ invcnt,
                                                      float4* __restrict__ out) {
    int i = blockIdx.x * 256 + threadIdx.x;
    if (i >= N_NODES) return;
    int b = i >> 7, l = i & 127;
    float a0 = 0.f, a1 = 0.f, a2 = 0.f, a3 = 0.f;
    #pragma unroll
    for (int sub = 0; sub < NSUB; sub++) {
        float4 p = pdec[(b * NSUB + sub) * 128 + l];
        a0 += p.x; a1 += p.y; a2 += p.z; a3 += p.w;
    }
    float ic = invcnt[i];
    out[i] = make_float4(a0 * ic, a1 * ic, a2 * ic, a3 * ic);
}

extern "C" void kernel_launch(void* const* d_in, const int* in_sizes, int n_in,
                              void* d_out, int out_size, void* d_ws, size_t ws_size,
                              hipStream_t stream) {
    const float* x    = (const float*)d_in[0];
    const int*   ei   = (const int*)d_in[1];
    const float* bn_w = (const float*)d_in[2];
    const float* bn_b = (const float*)d_in[3];
    const float* ew1  = (const float*)d_in[4];
    const float* eb1  = (const float*)d_in[5];
    const float* ew2  = (const float*)d_in[6];
    const float* eb2  = (const float*)d_in[7];
    const float* ew3  = (const float*)d_in[8];
    const float* eb3  = (const float*)d_in[9];
    const float* dw1  = (const float*)d_in[10];
    const float* db1  = (const float*)d_in[11];
    const float* dw2  = (const float*)d_in[12];
    const float* db2  = (const float*)d_in[13];
    const float* dw3  = (const float*)d_in[14];
    const float* db3  = (const float*)d_in[15];

    char* ws = (char*)d_ws;
    double* stats      = (double*)(ws + OFF_STATS);
    int*    bcnt       = (int*)(ws + OFF_BCNT);
    float*  invcnt     = (float*)(ws + OFF_INVCNT);
    float2* agg1       = (float2*)(ws + OFF_AGG1);
    float*  w1t        = (float*)(ws + OFF_W1T);
    float*  w2t        = (float*)(ws + OFF_W2T);
    float*  v1t        = (float*)(ws + OFF_V1T);
    float*  v2t        = (float*)(ws + OFF_V2T);
    int*    bucket_buf = (int*)(ws + OFF_BUCKET);
    float2* penc       = (float2*)(ws + OFF_PENC);
    int*    pcnt       = (int*)(ws + OFF_PCNT);
    float4* pdec       = (float4*)(ws + OFF_PDEC);
    float4* out        = (float4*)d_out;

    // zero: stats + bucket counts, contiguous [0, 5120)
    hipMemsetAsync(ws, 0, 5120, stream);

    k_prep<<<1, 1024, 0, stream>>>(ew1, ew2, dw1, dw2, w1t, w2t, v1t, v2t);
    k_bn_stats<<<NODE_BLOCKS, 256, 0, stream>>>(x, stats);
    k_s1<<<S1_BLOCKS, 256, 0, stream>>>(ei, bcnt, bucket_buf);
    k_enc_partial<<<dim3(NB, NSUB), 256, 0, stream>>>(x, stats, bn_w, bn_b,
                                                      bucket_buf, bcnt, penc, pcnt,
                                                      w1t, eb1, w2t, eb2, ew3, eb3);
    k_reduce_enc_p<<<NODE_BLOCKS, 256, 0, stream>>>(penc, pcnt, agg1, invcnt);
    k_dec_partial<<<dim3(NB, NSUB), 256, 0, stream>>>(agg1, bucket_buf, bcnt, pdec,
                                                      v1t, db1, v2t, db2, dw3, db3);
    k_reduce_dec_p<<<NODE_BLOCKS, 256, 0, stream>>>(pdec, invcnt, out);
}